// Round 12
// baseline (1761.660 us; speedup 1.0000x reference)
//
#include <hip/hip_runtime.h>
#include <math.h>

typedef _Float16 f16;
typedef f16 f16x4 __attribute__((ext_vector_type(4)));
typedef f16 f16x8 __attribute__((ext_vector_type(8)));
typedef float f32x4 __attribute__((ext_vector_type(4)));

#define MFMA16(a, b, c) __builtin_amdgcn_mfma_f32_16x16x32_f16((a), (b), (c), 0, 0, 0)

// ---------------------------------------------------------------------------
// ws layout (bytes):
//  Wg_t fp16[512][448]@0  Wg_a[256][160]@458752  Wg_v[256][448]@540672
//  W_a1[128][512]@770048  W_a2[512][128]@901120  W_b1[128][512]@1032192
//  W_b2[256][128]@1163264 W_g1[256][768]@1228800 W_g2[512][128]@1622016
//  W_o1[128][512]@1753088 bg f32[1024]@1884160
//  Hst f16[4096][256]@1888256  Cst f32@3985408  Mst f32@8179712
//  zx  f16[cs*4096][1024]@12374016
// ---------------------------------------------------------------------------

struct PackArgs {
  const float *t_Wih, *t_Whh, *t_b, *a_Wih, *a_Whh, *a_b, *v_Wih, *v_Whh, *v_b;
  const float *aW1, *aW2, *bW1, *bW2, *g1W1, *g2W1, *g1W2, *g2W2, *oW1;
  f16 *Wg_t, *Wg_a, *Wg_v, *W_a1, *W_a2, *W_b1, *W_b2, *W_g1, *W_g2, *W_o1;
  float *bg;
};

__global__ __launch_bounds__(256) void pack_w(PackArgs p) {
  int idx = blockIdx.x * 256 + threadIdx.x;
  if (idx < 229376) {  // Wg_t [512][448]
    int n = idx / 448, k = idx % 448;
    int srow = (n & 3) * 128 + (n >> 2);
    float v = (k < 300) ? p.t_Wih[srow * 300 + k]
                        : ((k >= 320) ? p.t_Whh[srow * 128 + k - 320] : 0.f);
    p.Wg_t[idx] = (f16)v; return;
  }
  idx -= 229376;
  if (idx < 40960) {  // Wg_a [256][160]
    int n = idx / 160, k = idx % 160;
    int srow = (n & 3) * 64 + (n >> 2);
    float v = (k < 81) ? p.a_Wih[srow * 81 + k]
                       : ((k >= 96) ? p.a_Whh[srow * 64 + k - 96] : 0.f);
    p.Wg_a[idx] = (f16)v; return;
  }
  idx -= 40960;
  if (idx < 114688) {  // Wg_v [256][448]
    int n = idx / 448, k = idx % 448;
    int srow = (n & 3) * 64 + (n >> 2);
    float v = (k < 371) ? p.v_Wih[srow * 371 + k]
                        : ((k >= 384) ? p.v_Whh[srow * 64 + k - 384] : 0.f);
    p.Wg_v[idx] = (f16)v; return;
  }
  idx -= 114688;
  if (idx < 65536) { p.W_a1[idx] = (f16)p.aW1[idx]; return; }
  idx -= 65536;
  if (idx < 65536) { p.W_a2[idx] = (f16)p.aW2[idx]; return; }
  idx -= 65536;
  if (idx < 65536) { p.W_b1[idx] = (f16)p.bW1[idx]; return; }
  idx -= 65536;
  if (idx < 32768) { p.W_b2[idx] = (f16)p.bW2[idx]; return; }
  idx -= 32768;
  if (idx < 196608) {  // W_g1 [256][768]
    int n = idx / 768;
    p.W_g1[idx] = (f16)((n < 128) ? p.g1W1[idx] : p.g2W1[idx - 98304]);
    return;
  }
  idx -= 196608;
  if (idx < 65536) {  // W_g2 [512][128]
    int n = idx / 128;
    p.W_g2[idx] = (f16)((n < 256) ? p.g1W2[idx] : p.g2W2[idx - 32768]);
    return;
  }
  idx -= 65536;
  if (idx < 65536) { p.W_o1[idx] = (f16)p.oW1[idx]; return; }
  idx -= 65536;
  if (idx < 1024) {
    int n = idx;
    float v;
    if (n < 512)      v = p.t_b[(n & 3) * 128 + (n >> 2)];
    else if (n < 768) { int m = n - 512; v = p.a_b[(m & 3) * 64 + (m >> 2)]; }
    else              { int m = n - 768; v = p.v_b[(m & 3) * 64 + (m >> 2)]; }
    p.bg[n] = v;
  }
}

// ===========================================================================
// zx GEMM (R7-proven): 32-row blocks, x staged once into LDS.
// ===========================================================================
struct ZxArgs { const float* x; const f16 *Wg_t, *Wg_a, *Wg_v; f16* zx; int t0; };

template <int KS, int KP, int XOFF>
__device__ __forceinline__ void zx_wave(const f16* __restrict__ Wg, int nc0, int n0g,
                                        const f16 (*Xs)[808], f16* __restrict__ zx,
                                        int mloc, int l15, int lg) {
#pragma unroll 1
  for (int half = 0; half < 2; ++half) {
    f32x4 acc[8];
#pragma unroll
    for (int j = 0; j < 8; ++j) acc[j] = (f32x4){0.f, 0.f, 0.f, 0.f};
#pragma unroll 1
    for (int ks = 0; ks < KS; ++ks) {
      f16x8 w[4];
#pragma unroll
      for (int i = 0; i < 4; ++i)
        w[i] = *(const f16x8*)(Wg + (size_t)(nc0 + 64 * half + 16 * i + l15) * KP + 32 * ks + 8 * lg);
      f16x8 a0 = *(const f16x8*)(&Xs[l15][XOFF + 32 * ks + 8 * lg]);
      f16x8 a1 = *(const f16x8*)(&Xs[16 + l15][XOFF + 32 * ks + 8 * lg]);
#pragma unroll
      for (int i = 0; i < 4; ++i) {
        acc[i] = MFMA16(a0, w[i], acc[i]);
        acc[4 + i] = MFMA16(a1, w[i], acc[4 + i]);
      }
    }
#pragma unroll
    for (int mt = 0; mt < 2; ++mt)
#pragma unroll
      for (int i = 0; i < 4; ++i) {
        int ng = n0g + 64 * half + 16 * i + l15;
#pragma unroll
        for (int q = 0; q < 4; ++q)
          zx[(size_t)(mloc + mt * 16 + 4 * lg + q) * 1024 + ng] = (f16)acc[mt * 4 + i][q];
      }
  }
}

__global__ __launch_bounds__(512, 2) void gemm_zx(ZxArgs z) {
  __shared__ f16 Xs[32][808];
  const int tid = threadIdx.x, wid = tid >> 6, lane = tid & 63, l15 = lane & 15, lg = lane >> 4;
  const int mloc = blockIdx.x * 32;
  {
    int r = tid >> 4;  // 0..31
    const float* xr = z.x + ((size_t)z.t0 * 4096 + mloc + r) * 752;
    for (int c = tid & 15; c < 800; c += 16) {
      float v;
      if (c < 320)      v = (c < 300) ? xr[c] : 0.f;
      else if (c < 416) { int s = c - 320; v = (s < 81) ? xr[300 + s] : 0.f; }
      else              { int s = c - 416; v = (s < 371) ? xr[381 + s] : 0.f; }
      Xs[r][c] = (f16)v;
    }
  }
  __syncthreads();
  if (wid < 4)
    zx_wave<10, 448, 0>(z.Wg_t, 128 * wid, 128 * wid, Xs, z.zx, mloc, l15, lg);
  else if (wid < 6)
    zx_wave<3, 160, 320>(z.Wg_a, 128 * (wid - 4), 512 + 128 * (wid - 4), Xs, z.zx, mloc, l15, lg);
  else
    zx_wave<12, 448, 416>(z.Wg_v, 128 * (wid - 6), 768 + 128 * (wid - 6), Xs, z.zx, mloc, l15, lg);
}

// ===========================================================================
// Recurrent kernel — 8-row blocks, 512 of them: 2 blocks/CU so independent
// blocks overlap each other's barrier-drain phases. 63 KB LDS, VGPR<=128.
// ===========================================================================
struct MainArgs {
  const float *x_p, *c_t, *c_a, *c_v, *mem0;
  const f16 *Wg_t, *Wg_a, *Wg_v, *W_a1, *W_a2, *W_b1, *W_b2, *W_g1, *W_g2, *W_o1;
  const float *bg, *a1b1, *a1b2, *a2b1, *a2b2, *g1b1, *g1b2, *g2b1, *g2b2, *ob1, *oW2, *ob2;
  f16 *Hst; float *Cst, *Mst; const f16 *zx;
  float *out;
};

__device__ __forceinline__ float sigm(float x) {
  return __builtin_amdgcn_rcpf(1.f + __expf(-x));
}
__device__ __forceinline__ float ftanh(float x) {
  float t = __expf(-2.f * fabsf(x));
  float r = (1.f - t) * __builtin_amdgcn_rcpf(1.f + t);
  return copysignf(r, x);
}

// ---- batched fc tile: W loads grouped (<=8 per group), A row = lr ----------
template <int KS, int LDA>
__device__ __forceinline__ f32x4 fc_tileB(const f16 (*Asrc)[LDA], int acol,
                                          const f16* Wrow, int lr, int lg) {
  f32x4 acc = {0.f, 0.f, 0.f, 0.f};
  constexpr int GB = (KS < 8) ? KS : 8;
  constexpr int G = (KS + GB - 1) / GB;
#pragma unroll
  for (int g = 0; g < G; ++g) {
    f16x8 w[GB];
#pragma unroll
    for (int j = 0; j < GB; ++j) w[j] = *(const f16x8*)(Wrow + 32 * (g * GB + j));
#pragma unroll
    for (int j = 0; j < GB; ++j) {
      f16x8 a = *(const f16x8*)(&Asrc[lr][acol + 8 * lg + 32 * (g * GB + j)]);
      acc = MFMA16(a, w[j], acc);
    }
  }
  return acc;
}

// ---- gate GEMM (h-part only), 4 tile-pairs, z from zx; 8-row guards --------
template <int KSH, int KP, int HOFF>
__device__ __forceinline__ void gmm_zxB(const f16* Wg, const float* bg, const f16* zxr,
                                        int nc0, int n0, int cub,
                                        int l15, int lg, int lr, int hb,
                                        const f16 (*hc)[264], f16 (*hn)[264],
                                        float (*cS)[260], f16 (*bufA)[808]) {
  f16x8 ah[KSH];
#pragma unroll
  for (int k = 0; k < KSH; ++k)
    ah[k] = *(const f16x8*)(&hc[lr][hb + 8 * lg + 32 * k]);
#pragma unroll 1
  for (int p = 0; p < 4; ++p) {
    const f16* r0 = Wg + (size_t)(nc0 + 32 * p + l15) * KP + HOFF + 8 * lg;
    const f16* r1 = r0 + (size_t)16 * KP;
    f16x8 w0[KSH], w1[KSH];
#pragma unroll
    for (int k = 0; k < KSH; ++k) {
      w0[k] = *(const f16x8*)(r0 + 32 * k);
      w1[k] = *(const f16x8*)(r1 + 32 * k);
    }
    f16x4 z0 = *(const f16x4*)(zxr + n0 + 32 * p + 4 * lg);
    f16x4 z1 = *(const f16x4*)(zxr + n0 + 32 * p + 16 + 4 * lg);
    f32x4 a0 = {0.f, 0.f, 0.f, 0.f}, a1 = {0.f, 0.f, 0.f, 0.f};
#pragma unroll
    for (int k = 0; k < KSH; ++k) {
      a0 = MFMA16(w0[k], ah[k], a0);
      a1 = MFMA16(w1[k], ah[k], a1);
    }
    if (l15 < 8) {  // D col = batch row = l15
      const float4 b0 = *(const float4*)&bg[n0 + 32 * p + 4 * lg];
      const float4 b1 = *(const float4*)&bg[n0 + 32 * p + 16 + 4 * lg];
      {
        float gi = sigm(a0[0] + (float)z0[0] + b0.x);
        float gf = sigm(a0[1] + (float)z0[1] + b0.y);
        float gg = ftanh(a0[2] + (float)z0[2] + b0.z);
        float go = sigm(a0[3] + (float)z0[3] + b0.w);
        int cu = cub + ((nc0 + 32 * p) >> 2) + lg;
        float cold = cS[l15][cu];
        float cnew = gf * cold + gi * gg;
        cS[l15][cu] = cnew;
        hn[l15][cu] = (f16)(go * ftanh(cnew));
        bufA[l15][cu] = (f16)cold;        // c_star = [pre_c | cur_c]
        bufA[l15][256 + cu] = (f16)cnew;
      }
      {
        float gi = sigm(a1[0] + (float)z1[0] + b1.x);
        float gf = sigm(a1[1] + (float)z1[1] + b1.y);
        float gg = ftanh(a1[2] + (float)z1[2] + b1.z);
        float go = sigm(a1[3] + (float)z1[3] + b1.w);
        int cu = cub + ((nc0 + 32 * p + 16) >> 2) + lg;
        float cold = cS[l15][cu];
        float cnew = gf * cold + gi * gg;
        cS[l15][cu] = cnew;
        hn[l15][cu] = (f16)(go * ftanh(cnew));
        bufA[l15][cu] = (f16)cold;
        bufA[l15][256 + cu] = (f16)cnew;
      }
    }
  }
}

__global__ __launch_bounds__(512, 2) void fused_seq(MainArgs A, int cs,
                                                    int first, int last) {
  // 8-row block: LDS ~63 KB -> 2 blocks/CU (VGPR<=128 required)
  __shared__ f16  h16a[8][264];
  __shared__ f16  h16b[8][264];
  __shared__ float cS[8][260];
  __shared__ float mS[8][260];
  __shared__ f16  bufA[8][808];     // cstar/attended (0:512) | m fp16 (512:768)
  __shared__ f16  hid16[8][264];
  __shared__ f16  ghid16[8][264];
  __shared__ float zf[8][516];

  const int tid = threadIdx.x;
  const int wid = tid >> 6, lane = tid & 63, l15 = lane & 15, lg = lane >> 4;
  const int lr = lane & 7;          // batch-row for reads (dup for upper lanes)
  const int r0 = blockIdx.x * 8;

  f16 (*hc)[264] = h16a;
  f16 (*hn)[264] = h16b;

  if (first) {
    for (int idx = tid; idx < 2048; idx += 512) {
      int r = idx >> 8, c = idx & 255, R = r0 + r;
      h16a[r][c] = (f16)0.f;
      float cv = (c < 128) ? A.c_t[R * 128 + c]
                           : (c < 192 ? A.c_a[R * 64 + c - 128] : A.c_v[R * 64 + c - 192]);
      cS[r][c] = cv;
      mS[r][c] = A.mem0[R * 256 + c];
    }
  } else {
    for (int idx = tid; idx < 2048; idx += 512) {
      int r = idx >> 8, c = idx & 255;
      size_t g = (size_t)(r0 + r) * 256 + c;
      h16a[r][c] = A.Hst[g];
      cS[r][c] = A.Cst[g];
      mS[r][c] = A.Mst[g];
    }
  }
  __syncthreads();

#pragma unroll 1
  for (int ts = 0; ts < cs; ++ts) {
    // ============== gates (h double-buffered: no pre-barrier) ==============
    {
      const f16* zxr = A.zx + ((size_t)ts * 4096 + r0 + lr) * 1024;
      if (wid < 4)
        gmm_zxB<4, 448, 320>(A.Wg_t, A.bg, zxr, 128 * wid, 128 * wid, 0,
                             l15, lg, lr, 0, hc, hn, cS, bufA);
      else if (wid < 6)
        gmm_zxB<2, 160, 96>(A.Wg_a, A.bg, zxr, 128 * (wid - 4), 512 + 128 * (wid - 4), 128,
                            l15, lg, lr, 128, hc, hn, cS, bufA);
      else
        gmm_zxB<2, 448, 384>(A.Wg_v, A.bg, zxr, 128 * (wid - 6), 768 + 128 * (wid - 6), 192,
                             l15, lg, lr, 192, hc, hn, cS, bufA);
    }
    __syncthreads();  // B1: bufA complete

    // ============== attn1 L1: hid = relu(cstar @ W^T + b) ==================
    {
      int n = 16 * wid;
      f32x4 acc = fc_tileB<16, 808>(bufA, 0, A.W_a1 + (size_t)(n + l15) * 512 + 8 * lg, lr, lg);
      if (lg < 2) {
        float b = A.a1b1[n + l15];
#pragma unroll
        for (int q = 0; q < 4; ++q) hid16[lg * 4 + q][n + l15] = (f16)fmaxf(acc[q] + b, 0.f);
      }
    }
    __syncthreads();  // B2

    // ============== attn1 L2: logits, 4 tiles/wave =========================
    {
#pragma unroll
      for (int i = 0; i < 4; ++i) {
        int n = 64 * wid + 16 * i + l15;
        f32x4 acc = fc_tileB<4, 264>(hid16, 0, A.W_a2 + (size_t)n * 128 + 8 * lg, lr, lg);
        if (lg < 2) {
          float b = A.a1b2[n];
#pragma unroll
          for (int q = 0; q < 4; ++q) zf[lg * 4 + q][n] = acc[q] + b;
        }
      }
    }
    __syncthreads();  // B3

    // ============== softmax * cstar (wave-per-row), m -> bufA[512:768] =====
    {
      int row = wid;  // 8 waves, 8 rows
      float v[8]; float mx = -1e30f;
#pragma unroll
      for (int j = 0; j < 8; ++j) { v[j] = zf[row][lane + 64 * j]; mx = fmaxf(mx, v[j]); }
#pragma unroll
      for (int m = 1; m < 64; m <<= 1) mx = fmaxf(mx, __shfl_xor(mx, m));
      float s = 0.f;
#pragma unroll
      for (int j = 0; j < 8; ++j) { v[j] = __expf(v[j] - mx); s += v[j]; }
#pragma unroll
      for (int m = 1; m < 64; m <<= 1) s += __shfl_xor(s, m);
      float inv = __builtin_amdgcn_rcpf(s);
#pragma unroll
      for (int j = 0; j < 8; ++j) {
        int c = lane + 64 * j;
        bufA[row][c] = (f16)(v[j] * inv * (float)bufA[row][c]);
      }
      for (int idx = tid; idx < 2048; idx += 512) {
        int r = idx >> 8, c = idx & 255;
        bufA[r][512 + c] = (f16)mS[r][c];
      }
    }
    __syncthreads();  // B4

    // ====== stage 6 (balanced): every wave 2 ghid tiles + 1 attn2L1 tile ===
    {
#pragma unroll 1
      for (int i = 0; i < 2; ++i) {
        int nn = 16 * (2 * wid + i) + l15;
        f32x4 acc = fc_tileB<24, 808>(bufA, 0, A.W_g1 + (size_t)nn * 768 + 8 * lg, lr, lg);
        if (lg < 2) {
          float b = (nn < 128) ? A.g1b1[nn] : A.g2b1[nn - 128];
#pragma unroll
          for (int q = 0; q < 4; ++q) ghid16[lg * 4 + q][nn] = (f16)fmaxf(acc[q] + b, 0.f);
        }
      }
      {
        int n = 16 * wid;
        f32x4 acc = fc_tileB<16, 808>(bufA, 0, A.W_b1 + (size_t)(n + l15) * 512 + 8 * lg, lr, lg);
        if (lg < 2) {
          float b = A.a2b1[n + l15];
#pragma unroll
          for (int q = 0; q < 4; ++q) hid16[lg * 4 + q][n + l15] = (f16)fmaxf(acc[q] + b, 0.f);
        }
      }
    }
    __syncthreads();  // B5

    // ====== stage 7: attn2 L2 + g1/g2 second layers + m-update (batched) ===
    {
#pragma unroll 1
      for (int i = 0; i < 2; ++i) {
        int n = 32 * wid + 16 * i + l15;
        const f16* wbp = A.W_b2 + (size_t)n * 128 + 8 * lg;
        const f16* w1p = A.W_g2 + (size_t)n * 128 + 8 * lg;
        const f16* w2p = A.W_g2 + (size_t)(256 + n) * 128 + 8 * lg;
        f16x8 wB[4], w1[4], w2[4];
#pragma unroll
        for (int k = 0; k < 4; ++k) {
          wB[k] = *(const f16x8*)(wbp + 32 * k);
          w1[k] = *(const f16x8*)(w1p + 32 * k);
          w2[k] = *(const f16x8*)(w2p + 32 * k);
        }
        f32x4 acB = {0.f, 0.f, 0.f, 0.f};
        f32x4 ac1 = {0.f, 0.f, 0.f, 0.f};
        f32x4 ac2 = {0.f, 0.f, 0.f, 0.f};
#pragma unroll
        for (int k = 0; k < 4; ++k) {
          f16x8 ha = *(const f16x8*)(&hid16[lr][8 * lg + 32 * k]);
          f16x8 ga1 = *(const f16x8*)(&ghid16[lr][8 * lg + 32 * k]);
          f16x8 ga2 = *(const f16x8*)(&ghid16[lr][128 + 8 * lg + 32 * k]);
          acB = MFMA16(ha, wB[k], acB);
          ac1 = MFMA16(ga1, w1[k], ac1);
          ac2 = MFMA16(ga2, w2[k], ac2);
        }
        if (lg < 2) {
          float bB = A.a2b2[n], b1 = A.g1b2[n], b2 = A.g2b2[n];
#pragma unroll
          for (int q = 0; q < 4; ++q) {
            int row = lg * 4 + q;
            float ch = ftanh(acB[q] + bB);
            float g1 = sigm(ac1[q] + b1);
            float g2 = sigm(ac2[q] + b2);
            mS[row][n] = g1 * mS[row][n] + g2 * ch;
          }
        }
      }
    }
    __syncthreads();  // B6 (loop end)

    { f16 (*tmp)[264] = hc; hc = hn; hn = tmp; }
  }

  if (last) {
    // ============== output head ===========================================
    for (int idx = tid; idx < 2048; idx += 512) {
      int r = idx >> 8, c = idx & 255;
      bufA[r][c] = hc[r][c];
      bufA[r][256 + c] = (f16)mS[r][c];
    }
    __syncthreads();
    {
      int n = 16 * wid;
      f32x4 acc = fc_tileB<16, 808>(bufA, 0, A.W_o1 + (size_t)(n + l15) * 512 + 8 * lg, lr, lg);
      if (lg < 2) {
        float b = A.ob1[n + l15];
#pragma unroll
        for (int q = 0; q < 4; ++q) hid16[lg * 4 + q][n + l15] = (f16)fmaxf(acc[q] + b, 0.f);
      }
    }
    __syncthreads();
    {
      int row = wid;  // 8 rows, one wave each
      float s = (float)hid16[row][lane] * A.oW2[lane] +
                (float)hid16[row][64 + lane] * A.oW2[64 + lane];
#pragma unroll
      for (int m = 1; m < 64; m <<= 1) s += __shfl_xor(s, m);
      if (lane == 0) A.out[r0 + row] = s + A.ob2[0];
    }
  } else {
    for (int idx = tid; idx < 2048; idx += 512) {
      int r = idx >> 8, c = idx & 255;
      size_t g = (size_t)(r0 + r) * 256 + c;
      A.Hst[g] = hc[r][c];
      A.Cst[g] = cS[r][c];
      A.Mst[g] = mS[r][c];
    }
  }
}

extern "C" void kernel_launch(void* const* d_in, const int* in_sizes, int n_in,
                              void* d_out, int out_size, void* d_ws, size_t ws_size,
                              hipStream_t stream) {
  (void)in_sizes; (void)n_in; (void)out_size;
  char* w = (char*)d_ws;
  f16* Wg_t = (f16*)(w + 0);
  f16* Wg_a = (f16*)(w + 458752);
  f16* Wg_v = (f16*)(w + 540672);
  f16* W_a1 = (f16*)(w + 770048);
  f16* W_a2 = (f16*)(w + 901120);
  f16* W_b1 = (f16*)(w + 1032192);
  f16* W_b2 = (f16*)(w + 1163264);
  f16* W_g1 = (f16*)(w + 1228800);
  f16* W_g2 = (f16*)(w + 1622016);
  f16* W_o1 = (f16*)(w + 1753088);
  float* bg = (float*)(w + 1884160);
  f16* Hst = (f16*)(w + 1888256);
  float* Cst = (float*)(w + 3985408);
  float* Mst = (float*)(w + 8179712);
  f16* zx = (f16*)(w + 12374016);

  size_t avail = (ws_size > 12374016) ? ws_size - 12374016 : 0;
  const size_t per_step = (size_t)4096 * 1024 * 2;
  int cs = 1;
  const int divs[6] = {20, 10, 5, 4, 2, 1};
  for (int i = 0; i < 6; ++i)
    if ((size_t)divs[i] * per_step <= avail) { cs = divs[i]; break; }

  PackArgs pa;
  pa.t_Wih = (const float*)d_in[5];  pa.t_Whh = (const float*)d_in[6];  pa.t_b = (const float*)d_in[7];
  pa.a_Wih = (const float*)d_in[8];  pa.a_Whh = (const float*)d_in[9];  pa.a_b = (const float*)d_in[10];
  pa.v_Wih = (const float*)d_in[11]; pa.v_Whh = (const float*)d_in[12]; pa.v_b = (const float*)d_in[13];
  pa.aW1 = (const float*)d_in[14];  pa.aW2 = (const float*)d_in[16];
  pa.bW1 = (const float*)d_in[18];  pa.bW2 = (const float*)d_in[20];
  pa.g1W1 = (const float*)d_in[22]; pa.g2W1 = (const float*)d_in[26];
  pa.g1W2 = (const float*)d_in[24]; pa.g2W2 = (const float*)d_in[28];
  pa.oW1 = (const float*)d_in[30];
  pa.Wg_t = Wg_t; pa.Wg_a = Wg_a; pa.Wg_v = Wg_v; pa.W_a1 = W_a1; pa.W_a2 = W_a2;
  pa.W_b1 = W_b1; pa.W_b2 = W_b2; pa.W_g1 = W_g1; pa.W_g2 = W_g2; pa.W_o1 = W_o1;
  pa.bg = bg;
  pack_w<<<3684, 256, 0, stream>>>(pa);

  MainArgs ma;
  ma.x_p = (const float*)d_in[0];
  ma.c_t = (const float*)d_in[1]; ma.c_a = (const float*)d_in[2]; ma.c_v = (const float*)d_in[3];
  ma.mem0 = (const float*)d_in[4];
  ma.Wg_t = Wg_t; ma.Wg_a = Wg_a; ma.Wg_v = Wg_v; ma.W_a1 = W_a1; ma.W_a2 = W_a2;
  ma.W_b1 = W_b1; ma.W_b2 = W_b2; ma.W_g1 = W_g1; ma.W_g2 = W_g2; ma.W_o1 = W_o1;
  ma.bg = bg;
  ma.a1b1 = (const float*)d_in[15]; ma.a1b2 = (const float*)d_in[17];
  ma.a2b1 = (const float*)d_in[19]; ma.a2b2 = (const float*)d_in[21];
  ma.g1b1 = (const float*)d_in[23]; ma.g1b2 = (const float*)d_in[25];
  ma.g2b1 = (const float*)d_in[27]; ma.g2b2 = (const float*)d_in[29];
  ma.ob1 = (const float*)d_in[31]; ma.oW2 = (const float*)d_in[32]; ma.ob2 = (const float*)d_in[33];
  ma.Hst = Hst; ma.Cst = Cst; ma.Mst = Mst; ma.zx = zx;
  ma.out = (float*)d_out;

  for (int t0 = 0; t0 < 20; t0 += cs) {
    ZxArgs za; za.x = (const float*)d_in[0];
    za.Wg_t = Wg_t; za.Wg_a = Wg_a; za.Wg_v = Wg_v; za.zx = zx; za.t0 = t0;
    gemm_zx<<<dim3(cs * 128), 512, 0, stream>>>(za);
    fused_seq<<<512, 512, 0, stream>>>(ma, cs, t0 == 0 ? 1 : 0,
                                       (t0 + cs >= 20) ? 1 : 0);
  }
}

// Round 13
// 1032.307 us; speedup vs baseline: 1.7065x; 1.7065x over previous
//
#include <hip/hip_runtime.h>
#include <math.h>

typedef _Float16 f16;
typedef f16 f16x4 __attribute__((ext_vector_type(4)));
typedef f16 f16x8 __attribute__((ext_vector_type(8)));
typedef float f32x4 __attribute__((ext_vector_type(4)));

#define MFMA16(a, b, c) __builtin_amdgcn_mfma_f32_16x16x32_f16((a), (b), (c), 0, 0, 0)

// ---------------------------------------------------------------------------
// ws layout (bytes):
//  Wg_t fp16[512][448]@0  Wg_a[256][160]@458752  Wg_v[256][448]@540672
//  W_a1[128][512]@770048  W_a2[512][128]@901120  W_b1[128][512]@1032192
//  W_b2[256][128]@1163264 W_g1[256][768]@1228800 W_g2[512][128]@1622016
//  W_o1[128][512]@1753088 bg f32[1024]@1884160
//  Hst f16[4096][256]@1888256  Cst f32@3985408  Mst f32@8179712
//  zx  f16[cs*4096][1024]@12374016
// ---------------------------------------------------------------------------

struct PackArgs {
  const float *t_Wih, *t_Whh, *t_b, *a_Wih, *a_Whh, *a_b, *v_Wih, *v_Whh, *v_b;
  const float *aW1, *aW2, *bW1, *bW2, *g1W1, *g2W1, *g1W2, *g2W2, *oW1;
  f16 *Wg_t, *Wg_a, *Wg_v, *W_a1, *W_a2, *W_b1, *W_b2, *W_g1, *W_g2, *W_o1;
  float *bg;
};

__global__ __launch_bounds__(256) void pack_w(PackArgs p) {
  int idx = blockIdx.x * 256 + threadIdx.x;
  if (idx < 229376) {  // Wg_t [512][448]
    int n = idx / 448, k = idx % 448;
    int srow = (n & 3) * 128 + (n >> 2);
    float v = (k < 300) ? p.t_Wih[srow * 300 + k]
                        : ((k >= 320) ? p.t_Whh[srow * 128 + k - 320] : 0.f);
    p.Wg_t[idx] = (f16)v; return;
  }
  idx -= 229376;
  if (idx < 40960) {  // Wg_a [256][160]
    int n = idx / 160, k = idx % 160;
    int srow = (n & 3) * 64 + (n >> 2);
    float v = (k < 81) ? p.a_Wih[srow * 81 + k]
                       : ((k >= 96) ? p.a_Whh[srow * 64 + k - 96] : 0.f);
    p.Wg_a[idx] = (f16)v; return;
  }
  idx -= 40960;
  if (idx < 114688) {  // Wg_v [256][448]
    int n = idx / 448, k = idx % 448;
    int srow = (n & 3) * 64 + (n >> 2);
    float v = (k < 371) ? p.v_Wih[srow * 371 + k]
                        : ((k >= 384) ? p.v_Whh[srow * 64 + k - 384] : 0.f);
    p.Wg_v[idx] = (f16)v; return;
  }
  idx -= 114688;
  if (idx < 65536) { p.W_a1[idx] = (f16)p.aW1[idx]; return; }
  idx -= 65536;
  if (idx < 65536) { p.W_a2[idx] = (f16)p.aW2[idx]; return; }
  idx -= 65536;
  if (idx < 65536) { p.W_b1[idx] = (f16)p.bW1[idx]; return; }
  idx -= 65536;
  if (idx < 32768) { p.W_b2[idx] = (f16)p.bW2[idx]; return; }
  idx -= 32768;
  if (idx < 196608) {  // W_g1 [256][768]
    int n = idx / 768;
    p.W_g1[idx] = (f16)((n < 128) ? p.g1W1[idx] : p.g2W1[idx - 98304]);
    return;
  }
  idx -= 196608;
  if (idx < 65536) {  // W_g2 [512][128]
    int n = idx / 128;
    p.W_g2[idx] = (f16)((n < 256) ? p.g1W2[idx] : p.g2W2[idx - 32768]);
    return;
  }
  idx -= 65536;
  if (idx < 65536) { p.W_o1[idx] = (f16)p.oW1[idx]; return; }
  idx -= 65536;
  if (idx < 1024) {
    int n = idx;
    float v;
    if (n < 512)      v = p.t_b[(n & 3) * 128 + (n >> 2)];
    else if (n < 768) { int m = n - 512; v = p.a_b[(m & 3) * 64 + (m >> 2)]; }
    else              { int m = n - 768; v = p.v_b[(m & 3) * 64 + (m >> 2)]; }
    p.bg[n] = v;
  }
}

// ===========================================================================
// zx GEMM: 32-row blocks, x staged once into LDS; per-block k-loop rotation
// de-lockstep (accumulation-order change only, ~ulp f32).
// ===========================================================================
struct ZxArgs { const float* x; const f16 *Wg_t, *Wg_a, *Wg_v; f16* zx; int t0; };

template <int KS, int KP, int XOFF>
__device__ __forceinline__ void zx_wave(const f16* __restrict__ Wg, int nc0, int n0g,
                                        const f16 (*Xs)[808], f16* __restrict__ zx,
                                        int mloc, int l15, int lg, int kst) {
#pragma unroll 1
  for (int half = 0; half < 2; ++half) {
    f32x4 acc[8];
#pragma unroll
    for (int j = 0; j < 8; ++j) acc[j] = (f32x4){0.f, 0.f, 0.f, 0.f};
#pragma unroll 1
    for (int kk = 0; kk < KS; ++kk) {
      int ks = kk + kst; if (ks >= KS) ks -= KS;
      f16x8 w[4];
#pragma unroll
      for (int i = 0; i < 4; ++i)
        w[i] = *(const f16x8*)(Wg + (size_t)(nc0 + 64 * half + 16 * i + l15) * KP + 32 * ks + 8 * lg);
      f16x8 a0 = *(const f16x8*)(&Xs[l15][XOFF + 32 * ks + 8 * lg]);
      f16x8 a1 = *(const f16x8*)(&Xs[16 + l15][XOFF + 32 * ks + 8 * lg]);
#pragma unroll
      for (int i = 0; i < 4; ++i) {
        acc[i] = MFMA16(a0, w[i], acc[i]);
        acc[4 + i] = MFMA16(a1, w[i], acc[4 + i]);
      }
    }
#pragma unroll
    for (int mt = 0; mt < 2; ++mt)
#pragma unroll
      for (int i = 0; i < 4; ++i) {
        int ng = n0g + 64 * half + 16 * i + l15;
#pragma unroll
        for (int q = 0; q < 4; ++q)
          zx[(size_t)(mloc + mt * 16 + 4 * lg + q) * 1024 + ng] = (f16)acc[mt * 4 + i][q];
      }
  }
}

__global__ __launch_bounds__(512, 2) void gemm_zx(ZxArgs z) {
  __shared__ f16 Xs[32][808];
  const int tid = threadIdx.x, wid = tid >> 6, lane = tid & 63, l15 = lane & 15, lg = lane >> 4;
  const int mloc = blockIdx.x * 32;
  {
    int r = tid >> 4;  // 0..31
    const float* xr = z.x + ((size_t)z.t0 * 4096 + mloc + r) * 752;
    for (int c = tid & 15; c < 800; c += 16) {
      float v;
      if (c < 320)      v = (c < 300) ? xr[c] : 0.f;
      else if (c < 416) { int s = c - 320; v = (s < 81) ? xr[300 + s] : 0.f; }
      else              { int s = c - 416; v = (s < 371) ? xr[381 + s] : 0.f; }
      Xs[r][c] = (f16)v;
    }
  }
  __syncthreads();
  if (wid < 4)
    zx_wave<10, 448, 0>(z.Wg_t, 128 * wid, 128 * wid, Xs, z.zx, mloc, l15, lg,
                        (int)(blockIdx.x % 10u));
  else if (wid < 6)
    zx_wave<3, 160, 320>(z.Wg_a, 128 * (wid - 4), 512 + 128 * (wid - 4), Xs, z.zx, mloc, l15, lg,
                         (int)(blockIdx.x % 3u));
  else
    zx_wave<12, 448, 416>(z.Wg_v, 128 * (wid - 6), 768 + 128 * (wid - 6), Xs, z.zx, mloc, l15, lg,
                          (int)(blockIdx.x % 12u));
}

// ===========================================================================
// Recurrent kernel — R11 structure (16-row blocks, 8 waves, h double-buffer)
// + per-block wave->tile rotation (de-lockstep; bijective, bitwise-identical).
// ===========================================================================
struct MainArgs {
  const float *x_p, *c_t, *c_a, *c_v, *mem0;
  const f16 *Wg_t, *Wg_a, *Wg_v, *W_a1, *W_a2, *W_b1, *W_b2, *W_g1, *W_g2, *W_o1;
  const float *bg, *a1b1, *a1b2, *a2b1, *a2b2, *g1b1, *g1b2, *g2b1, *g2b2, *ob1, *oW2, *ob2;
  f16 *Hst; float *Cst, *Mst; const f16 *zx;
  float *out;
};

__device__ __forceinline__ float sigm(float x) {
  return __builtin_amdgcn_rcpf(1.f + __expf(-x));
}
__device__ __forceinline__ float ftanh(float x) {
  float t = __expf(-2.f * fabsf(x));
  float r = (1.f - t) * __builtin_amdgcn_rcpf(1.f + t);
  return copysignf(r, x);
}

// ---- batched fc tile: W loads grouped (<=8 per group), A from LDS ----------
template <int KS, int LDA>
__device__ __forceinline__ f32x4 fc_tileB(const f16 (*Asrc)[LDA], int acol,
                                          const f16* Wrow, int l15, int lg) {
  f32x4 acc = {0.f, 0.f, 0.f, 0.f};
  constexpr int GB = (KS < 8) ? KS : 8;
  constexpr int G = (KS + GB - 1) / GB;
#pragma unroll
  for (int g = 0; g < G; ++g) {
    f16x8 w[GB];
#pragma unroll
    for (int j = 0; j < GB; ++j) w[j] = *(const f16x8*)(Wrow + 32 * (g * GB + j));
#pragma unroll
    for (int j = 0; j < GB; ++j) {
      f16x8 a = *(const f16x8*)(&Asrc[l15][acol + 8 * lg + 32 * (g * GB + j)]);
      acc = MFMA16(a, w[j], acc);
    }
  }
  return acc;
}

// ---- gate GEMM (h-part only), 4 tile-pairs with batched W, z from zx -------
template <int KSH, int KP, int HOFF>
__device__ __forceinline__ void gmm_zxB(const f16* Wg, const float* bg, const f16* zxr,
                                        int nc0, int n0, int cub,
                                        int l15, int lg, int hb,
                                        const f16 (*hc)[264], f16 (*hn)[264],
                                        float (*cS)[260], f16 (*bufA)[808]) {
  f16x8 ah[KSH];
#pragma unroll
  for (int k = 0; k < KSH; ++k)
    ah[k] = *(const f16x8*)(&hc[l15][hb + 8 * lg + 32 * k]);
#pragma unroll 1
  for (int p = 0; p < 4; ++p) {
    const f16* r0 = Wg + (size_t)(nc0 + 32 * p + l15) * KP + HOFF + 8 * lg;
    const f16* r1 = r0 + (size_t)16 * KP;
    f16x8 w0[KSH], w1[KSH];
#pragma unroll
    for (int k = 0; k < KSH; ++k) {
      w0[k] = *(const f16x8*)(r0 + 32 * k);
      w1[k] = *(const f16x8*)(r1 + 32 * k);
    }
    f16x4 z0 = *(const f16x4*)(zxr + n0 + 32 * p + 4 * lg);
    f16x4 z1 = *(const f16x4*)(zxr + n0 + 32 * p + 16 + 4 * lg);
    f32x4 a0 = {0.f, 0.f, 0.f, 0.f}, a1 = {0.f, 0.f, 0.f, 0.f};
#pragma unroll
    for (int k = 0; k < KSH; ++k) {
      a0 = MFMA16(w0[k], ah[k], a0);
      a1 = MFMA16(w1[k], ah[k], a1);
    }
    const float4 b0 = *(const float4*)&bg[n0 + 32 * p + 4 * lg];
    const float4 b1 = *(const float4*)&bg[n0 + 32 * p + 16 + 4 * lg];
    {
      float gi = sigm(a0[0] + (float)z0[0] + b0.x);
      float gf = sigm(a0[1] + (float)z0[1] + b0.y);
      float gg = ftanh(a0[2] + (float)z0[2] + b0.z);
      float go = sigm(a0[3] + (float)z0[3] + b0.w);
      int cu = cub + ((nc0 + 32 * p) >> 2) + lg;
      float cold = cS[l15][cu];
      float cnew = gf * cold + gi * gg;
      cS[l15][cu] = cnew;
      hn[l15][cu] = (f16)(go * ftanh(cnew));
      bufA[l15][cu] = (f16)cold;        // c_star = [pre_c | cur_c]
      bufA[l15][256 + cu] = (f16)cnew;
    }
    {
      float gi = sigm(a1[0] + (float)z1[0] + b1.x);
      float gf = sigm(a1[1] + (float)z1[1] + b1.y);
      float gg = ftanh(a1[2] + (float)z1[2] + b1.z);
      float go = sigm(a1[3] + (float)z1[3] + b1.w);
      int cu = cub + ((nc0 + 32 * p + 16) >> 2) + lg;
      float cold = cS[l15][cu];
      float cnew = gf * cold + gi * gg;
      cS[l15][cu] = cnew;
      hn[l15][cu] = (f16)(go * ftanh(cnew));
      bufA[l15][cu] = (f16)cold;
      bufA[l15][256 + cu] = (f16)cnew;
    }
  }
}

__global__ __launch_bounds__(512, 2) void fused_seq(MainArgs A, int cs,
                                                    int first, int last) {
  __shared__ f16  h16a[16][264];    // h double-buffer
  __shared__ f16  h16b[16][264];
  __shared__ float cS[16][260];
  __shared__ float mS[16][260];
  __shared__ f16  bufA[16][808];    // cstar/attended (0:512) | m fp16 (512:768)
  __shared__ f16  hid16[16][264];
  __shared__ f16  ghid16[16][264];
  __shared__ float zf[16][516];

  const int tid = threadIdx.x;
  const int wid = tid >> 6, lane = tid & 63, l15 = lane & 15, lg = lane >> 4;
  const int r0 = blockIdx.x * 16;
  const int rot = blockIdx.x & 7;   // de-lockstep salt

  // rotated (bijective) wave->tile role indices
  const int gtw = (wid + rot) & 3;          // gates t (waves 0-3)
  const int gaw = (wid - 4 + rot) & 1;      // gates a (waves 4,5)
  const int gvw = (wid - 6 + rot) & 1;      // gates v (waves 6,7)
  const int rw8 = (wid + rot) & 7;          // generic 8-tile rotation

  f16 (*hc)[264] = h16a;
  f16 (*hn)[264] = h16b;

  if (first) {
    for (int idx = tid; idx < 4096; idx += 512) {
      int r = idx >> 8, c = idx & 255, R = r0 + r;
      h16a[r][c] = (f16)0.f;
      float cv = (c < 128) ? A.c_t[R * 128 + c]
                           : (c < 192 ? A.c_a[R * 64 + c - 128] : A.c_v[R * 64 + c - 192]);
      cS[r][c] = cv;
      mS[r][c] = A.mem0[R * 256 + c];
    }
  } else {
    for (int idx = tid; idx < 4096; idx += 512) {
      int r = idx >> 8, c = idx & 255;
      size_t g = (size_t)(r0 + r) * 256 + c;
      h16a[r][c] = A.Hst[g];
      cS[r][c] = A.Cst[g];
      mS[r][c] = A.Mst[g];
    }
  }
  __syncthreads();

#pragma unroll 1
  for (int ts = 0; ts < cs; ++ts) {
    // ============== gates (h double-buffered: no pre-barrier) ==============
    {
      const f16* zxr = A.zx + ((size_t)ts * 4096 + r0 + l15) * 1024;
      if (wid < 4)
        gmm_zxB<4, 448, 320>(A.Wg_t, A.bg, zxr, 128 * gtw, 128 * gtw, 0,
                             l15, lg, 0, hc, hn, cS, bufA);
      else if (wid < 6)
        gmm_zxB<2, 160, 96>(A.Wg_a, A.bg, zxr, 128 * gaw, 512 + 128 * gaw, 128,
                            l15, lg, 128, hc, hn, cS, bufA);
      else
        gmm_zxB<2, 448, 384>(A.Wg_v, A.bg, zxr, 128 * gvw, 768 + 128 * gvw, 192,
                             l15, lg, 192, hc, hn, cS, bufA);
    }
    __syncthreads();  // B1: bufA complete

    // ============== attn1 L1: hid = relu(cstar @ W^T + b) (rotated) ========
    {
      int n = 16 * rw8;
      f32x4 acc = fc_tileB<16, 808>(bufA, 0, A.W_a1 + (size_t)(n + l15) * 512 + 8 * lg, l15, lg);
      float b = A.a1b1[n + l15];
#pragma unroll
      for (int q = 0; q < 4; ++q) hid16[lg * 4 + q][n + l15] = (f16)fmaxf(acc[q] + b, 0.f);
    }
    __syncthreads();  // B2

    // ============== attn1 L2: logits, 4 tiles/wave (rotated) ===============
    {
#pragma unroll
      for (int i = 0; i < 4; ++i) {
        int n = 64 * rw8 + 16 * i + l15;
        f32x4 acc = fc_tileB<4, 264>(hid16, 0, A.W_a2 + (size_t)n * 128 + 8 * lg, l15, lg);
        float b = A.a1b2[n];
#pragma unroll
        for (int q = 0; q < 4; ++q) zf[lg * 4 + q][n] = acc[q] + b;
      }
    }
    __syncthreads();  // B3

    // ============== softmax * cstar (in place), m -> bufA[512:768] =========
    {
      int row = tid >> 5, c0 = tid & 31;
      float v[16]; float mx = -1e30f;
#pragma unroll
      for (int j = 0; j < 16; ++j) { v[j] = zf[row][c0 + 32 * j]; mx = fmaxf(mx, v[j]); }
#pragma unroll
      for (int m = 1; m < 32; m <<= 1) mx = fmaxf(mx, __shfl_xor(mx, m));
      float s = 0.f;
#pragma unroll
      for (int j = 0; j < 16; ++j) { v[j] = __expf(v[j] - mx); s += v[j]; }
#pragma unroll
      for (int m = 1; m < 32; m <<= 1) s += __shfl_xor(s, m);
      float inv = __builtin_amdgcn_rcpf(s);
#pragma unroll
      for (int j = 0; j < 16; ++j) {
        int c = c0 + 32 * j;
        bufA[row][c] = (f16)(v[j] * inv * (float)bufA[row][c]);
      }
      for (int idx = tid; idx < 4096; idx += 512) {
        int r = idx >> 8, c = idx & 255;
        bufA[r][512 + c] = (f16)mS[r][c];
      }
    }
    __syncthreads();  // B4

    // ====== stage 6: every wave 2 ghid tiles + 1 attn2L1 tile (rotated) ====
    {
#pragma unroll 1
      for (int i = 0; i < 2; ++i) {
        int nn = 16 * (2 * rw8 + i) + l15;
        f32x4 acc = fc_tileB<24, 808>(bufA, 0, A.W_g1 + (size_t)nn * 768 + 8 * lg, l15, lg);
        float b = (nn < 128) ? A.g1b1[nn] : A.g2b1[nn - 128];
#pragma unroll
        for (int q = 0; q < 4; ++q) ghid16[lg * 4 + q][nn] = (f16)fmaxf(acc[q] + b, 0.f);
      }
      {
        int n = 16 * rw8;
        f32x4 acc = fc_tileB<16, 808>(bufA, 0, A.W_b1 + (size_t)(n + l15) * 512 + 8 * lg, l15, lg);
        float b = A.a2b1[n + l15];
#pragma unroll
        for (int q = 0; q < 4; ++q) hid16[lg * 4 + q][n + l15] = (f16)fmaxf(acc[q] + b, 0.f);
      }
    }
    __syncthreads();  // B5

    // ====== stage 7: attn2 L2 + g1/g2 second layers + m-update (rotated) ===
    {
#pragma unroll 1
      for (int i = 0; i < 2; ++i) {
        int n = 32 * rw8 + 16 * i + l15;
        const f16* wbp = A.W_b2 + (size_t)n * 128 + 8 * lg;
        const f16* w1p = A.W_g2 + (size_t)n * 128 + 8 * lg;
        const f16* w2p = A.W_g2 + (size_t)(256 + n) * 128 + 8 * lg;
        f16x8 wB[4], w1[4], w2[4];
#pragma unroll
        for (int k = 0; k < 4; ++k) {
          wB[k] = *(const f16x8*)(wbp + 32 * k);
          w1[k] = *(const f16x8*)(w1p + 32 * k);
          w2[k] = *(const f16x8*)(w2p + 32 * k);
        }
        f32x4 acB = {0.f, 0.f, 0.f, 0.f};
        f32x4 ac1 = {0.f, 0.f, 0.f, 0.f};
        f32x4 ac2 = {0.f, 0.f, 0.f, 0.f};
#pragma unroll
        for (int k = 0; k < 4; ++k) {
          f16x8 ha = *(const f16x8*)(&hid16[l15][8 * lg + 32 * k]);
          f16x8 ga1 = *(const f16x8*)(&ghid16[l15][8 * lg + 32 * k]);
          f16x8 ga2 = *(const f16x8*)(&ghid16[l15][128 + 8 * lg + 32 * k]);
          acB = MFMA16(ha, wB[k], acB);
          ac1 = MFMA16(ga1, w1[k], ac1);
          ac2 = MFMA16(ga2, w2[k], ac2);
        }
        float bB = A.a2b2[n], b1 = A.g1b2[n], b2 = A.g2b2[n];
#pragma unroll
        for (int q = 0; q < 4; ++q) {
          int row = lg * 4 + q;
          float ch = ftanh(acB[q] + bB);
          float g1 = sigm(ac1[q] + b1);
          float g2 = sigm(ac2[q] + b2);
          mS[row][n] = g1 * mS[row][n] + g2 * ch;
        }
      }
    }
    __syncthreads();  // B6 (loop end)

    { f16 (*tmp)[264] = hc; hc = hn; hn = tmp; }
  }

  if (last) {
    // ============== output head ===========================================
    for (int idx = tid; idx < 4096; idx += 512) {
      int r = idx >> 8, c = idx & 255;
      bufA[r][c] = hc[r][c];
      bufA[r][256 + c] = (f16)mS[r][c];
    }
    __syncthreads();
    {
      int n = 16 * rw8;
      f32x4 acc = fc_tileB<16, 808>(bufA, 0, A.W_o1 + (size_t)(n + l15) * 512 + 8 * lg, l15, lg);
      float b = A.ob1[n + l15];
#pragma unroll
      for (int q = 0; q < 4; ++q) hid16[lg * 4 + q][n + l15] = (f16)fmaxf(acc[q] + b, 0.f);
    }
    __syncthreads();
    {
      int row = tid >> 5, c0 = tid & 31;
      float s = 0.f;
#pragma unroll
      for (int j = 0; j < 4; ++j) { int k = c0 + 32 * j; s += (float)hid16[row][k] * A.oW2[k]; }
#pragma unroll
      for (int m = 1; m < 32; m <<= 1) s += __shfl_xor(s, m);
      if (c0 == 0) A.out[r0 + row] = s + A.ob2[0];
    }
  } else {
    for (int idx = tid; idx < 4096; idx += 512) {
      int r = idx >> 8, c = idx & 255;
      size_t g = (size_t)(r0 + r) * 256 + c;
      A.Hst[g] = hc[r][c];
      A.Cst[g] = cS[r][c];
      A.Mst[g] = mS[r][c];
    }
  }
}

extern "C" void kernel_launch(void* const* d_in, const int* in_sizes, int n_in,
                              void* d_out, int out_size, void* d_ws, size_t ws_size,
                              hipStream_t stream) {
  (void)in_sizes; (void)n_in; (void)out_size;
  char* w = (char*)d_ws;
  f16* Wg_t = (f16*)(w + 0);
  f16* Wg_a = (f16*)(w + 458752);
  f16* Wg_v = (f16*)(w + 540672);
  f16* W_a1 = (f16*)(w + 770048);
  f16* W_a2 = (f16*)(w + 901120);
  f16* W_b1 = (f16*)(w + 1032192);
  f16* W_b2 = (f16*)(w + 1163264);
  f16* W_g1 = (f16*)(w + 1228800);
  f16* W_g2 = (f16*)(w + 1622016);
  f16* W_o1 = (f16*)(w + 1753088);
  float* bg = (float*)(w + 1884160);
  f16* Hst = (f16*)(w + 1888256);
  float* Cst = (float*)(w + 3985408);
  float* Mst = (float*)(w + 8179712);
  f16* zx = (f16*)(w + 12374016);

  size_t avail = (ws_size > 12374016) ? ws_size - 12374016 : 0;
  const size_t per_step = (size_t)4096 * 1024 * 2;
  int cs = 1;
  const int divs[6] = {20, 10, 5, 4, 2, 1};
  for (int i = 0; i < 6; ++i)
    if ((size_t)divs[i] * per_step <= avail) { cs = divs[i]; break; }

  PackArgs pa;
  pa.t_Wih = (const float*)d_in[5];  pa.t_Whh = (const float*)d_in[6];  pa.t_b = (const float*)d_in[7];
  pa.a_Wih = (const float*)d_in[8];  pa.a_Whh = (const float*)d_in[9];  pa.a_b = (const float*)d_in[10];
  pa.v_Wih = (const float*)d_in[11]; pa.v_Whh = (const float*)d_in[12]; pa.v_b = (const float*)d_in[13];
  pa.aW1 = (const float*)d_in[14];  pa.aW2 = (const float*)d_in[16];
  pa.bW1 = (const float*)d_in[18];  pa.bW2 = (const float*)d_in[20];
  pa.g1W1 = (const float*)d_in[22]; pa.g2W1 = (const float*)d_in[26];
  pa.g1W2 = (const float*)d_in[24]; pa.g2W2 = (const float*)d_in[28];
  pa.oW1 = (const float*)d_in[30];
  pa.Wg_t = Wg_t; pa.Wg_a = Wg_a; pa.Wg_v = Wg_v; pa.W_a1 = W_a1; pa.W_a2 = W_a2;
  pa.W_b1 = W_b1; pa.W_b2 = W_b2; pa.W_g1 = W_g1; pa.W_g2 = W_g2; pa.W_o1 = W_o1;
  pa.bg = bg;
  pack_w<<<3684, 256, 0, stream>>>(pa);

  MainArgs ma;
  ma.x_p = (const float*)d_in[0];
  ma.c_t = (const float*)d_in[1]; ma.c_a = (const float*)d_in[2]; ma.c_v = (const float*)d_in[3];
  ma.mem0 = (const float*)d_in[4];
  ma.Wg_t = Wg_t; ma.Wg_a = Wg_a; ma.Wg_v = Wg_v; ma.W_a1 = W_a1; ma.W_a2 = W_a2;
  ma.W_b1 = W_b1; ma.W_b2 = W_b2; ma.W_g1 = W_g1; ma.W_g2 = W_g2; ma.W_o1 = W_o1;
  ma.bg = bg;
  ma.a1b1 = (const float*)d_in[15]; ma.a1b2 = (const float*)d_in[17];
  ma.a2b1 = (const float*)d_in[19]; ma.a2b2 = (const float*)d_in[21];
  ma.g1b1 = (const float*)d_in[23]; ma.g1b2 = (const float*)d_in[25];
  ma.g2b1 = (const float*)d_in[27]; ma.g2b2 = (const float*)d_in[29];
  ma.ob1 = (const float*)d_in[31]; ma.oW2 = (const float*)d_in[32]; ma.ob2 = (const float*)d_in[33];
  ma.Hst = Hst; ma.Cst = Cst; ma.Mst = Mst; ma.zx = zx;
  ma.out = (float*)d_out;

  for (int t0 = 0; t0 < 20; t0 += cs) {
    ZxArgs za; za.x = (const float*)d_in[0];
    za.Wg_t = Wg_t; za.Wg_a = Wg_a; za.Wg_v = Wg_v; za.zx = zx; za.t0 = t0;
    gemm_zx<<<dim3(cs * 128), 512, 0, stream>>>(za);
    fused_seq<<<256, 512, 0, stream>>>(ma, cs, t0 == 0 ? 1 : 0,
                                       (t0 + cs >= 20) ? 1 : 0);
  }
}